// Round 1
// baseline (484.348 us; speedup 1.0000x reference)
//
#include <hip/hip_runtime.h>
#include <math.h>

#define BS 32
#define Q  600
#define NC 152
#define T  32
#define MT (BS*T)              // 1024 targets total
#define CM_SIZE ((size_t)BS*Q*MT)  // 19660800 elements per cost matrix

// ---------------------------------------------------------------------------
// Kernel A: build cost matrices. One block per (q, b, mat).
//   C[b,q,t] = L1(box, tbox) - prob[class] - GIoU(box, tbox)
// Also stages transposed diagonal blocks [mat][b][t][q] into ws for the LSA.
// ---------------------------------------------------------------------------
__global__ __launch_bounds__(256) void cost_kernel(
    const float* __restrict__ logits_s, const float* __restrict__ logits_o,
    const float* __restrict__ boxes_s,  const float* __restrict__ boxes_o,
    const float* __restrict__ tbb_s,    const float* __restrict__ tbb_o,
    const int*   __restrict__ tids_s,   const int*   __restrict__ tids_o,
    float* __restrict__ C_s, float* __restrict__ C_o,
    float* __restrict__ blockT, int use_staged)
{
    const int q = blockIdx.x, b = blockIdx.y, mat = blockIdx.z;
    const int tid = threadIdx.x;

    const float* logits = mat ? logits_o : logits_s;
    const float* boxes  = mat ? boxes_o  : boxes_s;
    const float* tbb    = mat ? tbb_o    : tbb_s;
    const int*   tids   = mat ? tids_o   : tids_s;
    float* C = mat ? C_o : C_s;

    const int row = b*Q + q;
    const float* lrow = logits + (size_t)row*NC;

    __shared__ float red[256];
    __shared__ float slog[NC];
    __shared__ float sbox[4];

    float lv = (tid < NC) ? lrow[tid] : -INFINITY;
    if (tid < NC) slog[tid] = lv;
    if (tid < 4)  sbox[tid] = boxes[(size_t)row*4 + tid];
    red[tid] = lv;
    __syncthreads();
    for (int s = 128; s > 0; s >>= 1) {
        if (tid < s) red[tid] = fmaxf(red[tid], red[tid+s]);
        __syncthreads();
    }
    const float m = red[0];
    __syncthreads();
    red[tid] = (tid < NC) ? expf(lv - m) : 0.0f;
    __syncthreads();
    for (int s = 128; s > 0; s >>= 1) {
        if (tid < s) red[tid] += red[tid+s];
        __syncthreads();
    }
    const float ssum = red[0];

    const float ocx = sbox[0], ocy = sbox[1], ow = sbox[2], oh = sbox[3];
    const float ox1 = ocx - 0.5f*ow, oy1 = ocy - 0.5f*oh;
    const float ox2 = ocx + 0.5f*ow, oy2 = ocy + 0.5f*oh;
    const float area1 = (ox2-ox1)*(oy2-oy1);

    for (int t = tid; t < MT; t += 256) {
        const int cls = tids[t];
        const float cc = -(expf(slog[cls] - m) / ssum);

        const float4 tb = ((const float4*)tbb)[t];
        const float cb = fabsf(ocx-tb.x) + fabsf(ocy-tb.y)
                       + fabsf(ow -tb.z) + fabsf(oh -tb.w);

        const float tx1 = tb.x - 0.5f*tb.z, ty1 = tb.y - 0.5f*tb.w;
        const float tx2 = tb.x + 0.5f*tb.z, ty2 = tb.y + 0.5f*tb.w;
        const float area2 = (tx2-tx1)*(ty2-ty1);

        const float ltx = fmaxf(ox1,tx1), lty = fmaxf(oy1,ty1);
        const float rbx = fminf(ox2,tx2), rby = fminf(oy2,ty2);
        const float iw = fmaxf(rbx-ltx, 0.0f), ih = fmaxf(rby-lty, 0.0f);
        const float inter = iw*ih;
        const float uni = area1 + area2 - inter;
        const float iou = inter/uni;

        const float cx1 = fminf(ox1,tx1), cy1 = fminf(oy1,ty1);
        const float cx2 = fmaxf(ox2,tx2), cy2 = fmaxf(oy2,ty2);
        const float cw = fmaxf(cx2-cx1, 0.0f), ch = fmaxf(cy2-cy1, 0.0f);
        const float areac = cw*ch;
        const float giou = iou - (areac - uni)/areac;

        const float cost = cb + cc - giou;
        C[(size_t)row*MT + t] = cost;
        if (use_staged && (t >> 5) == b) {
            const int tl = t & 31;
            blockT[(((size_t)mat*BS + b)*T + tl)*Q + q] = cost;
        }
    }
}

// ---------------------------------------------------------------------------
// Kernel B: Jonker-Volgenant shortest-augmenting-path LSA.
// One wave (64 threads) per problem; 64 problems = (2 matrices x 32 batches).
// Faithful port of the reference's algorithm incl. np.argmin first-index
// tie-break. Double precision internals (matches f64 cast of f32 cost).
// ---------------------------------------------------------------------------
__global__ __launch_bounds__(64) void lsa_kernel(
    const float* __restrict__ blockT, const float* __restrict__ Cbase,
    float* __restrict__ idx_out, int use_staged)
{
    const int prob = blockIdx.x;        // 0..63
    const int mat = prob >> 5, b = prob & 31;
    const int tid = threadIdx.x;
    const int N = T, M = Q;

    __shared__ double u[T+1];
    __shared__ double v[Q+1];
    __shared__ double minv[Q+1];
    __shared__ int p[Q+1];
    __shared__ int way[Q+1];
    __shared__ int used[Q+1];

    for (int j = tid; j <= M; j += 64) { v[j] = 0.0; p[j] = 0; way[j] = 0; }
    if (tid <= N) u[tid] = 0.0;
    __syncthreads();

    const float* cb;
    long rowStride, colStride;
    if (use_staged) {
        cb = blockT + (size_t)prob * T * Q;
        rowStride = Q; colStride = 1;
    } else {
        // block[t][q] = C[b, q, b*T + t]
        cb = Cbase + (size_t)mat*CM_SIZE + (size_t)b*Q*MT + (size_t)b*T;
        rowStride = 1; colStride = MT;
    }

    const double DINF = 1e18;
    for (int i = 1; i <= N; ++i) {
        for (int j = tid; j <= M; j += 64) { minv[j] = DINF; used[j] = 0; }
        if (tid == 0) p[0] = i;
        __syncthreads();

        int j0 = 0;
        while (true) {
            if (tid == 0) used[j0] = 1;
            const int i0 = p[j0];
            __syncthreads();

            const double ui0 = u[i0];
            const float* crow = cb + (size_t)(i0-1)*rowStride;

            double best = DINF; int bestj = M + 1;
            for (int j = 1 + tid; j <= M; j += 64) {
                if (!used[j]) {
                    const double cur = (double)crow[(size_t)(j-1)*colStride] - ui0 - v[j];
                    if (cur < minv[j]) { minv[j] = cur; way[j] = j0; }
                    const double mv = minv[j];
                    if (mv < best) { best = mv; bestj = j; }  // j ascends in-lane
                }
            }
            // wave argmin, lowest-index tie-break (np.argmin semantics)
            for (int off = 32; off > 0; off >>= 1) {
                const double ov = __shfl_down(best, off);
                const int    oj = __shfl_down(bestj, off);
                if (ov < best || (ov == best && oj < bestj)) { best = ov; bestj = oj; }
            }
            const double delta = __shfl(best, 0);
            const int j1 = __shfl(bestj, 0);
            __syncthreads();

            for (int j = tid; j <= M; j += 64) {
                if (used[j]) { u[p[j]] += delta; v[j] -= delta; }  // distinct p[j] -> no collision
                else         { minv[j] -= delta; }
            }
            __syncthreads();

            j0 = j1;
            if (p[j0] == 0) break;   // p is stable during the while loop
        }

        if (tid == 0) {
            int jj = j0;
            while (jj != 0) { const int jp = way[jj]; p[jj] = p[jp]; jj = jp; }
        }
        __syncthreads();
    }

    if (tid == 0) {
        float* pred = idx_out + (size_t)mat * 2 * BS * T;  // ps (mat 0) / po (mat 1)
        float* tgt  = pred + BS * T;                       // ts / to
        int k = 0;
        for (int j = 1; j <= M; ++j) {
            if (p[j] != 0) {
                pred[b*T + k] = (float)(j - 1);
                tgt [b*T + k] = (float)(p[j] - 1);
                ++k;
            }
        }
    }
}

extern "C" void kernel_launch(void* const* d_in, const int* in_sizes, int n_in,
                              void* d_out, int out_size, void* d_ws, size_t ws_size,
                              hipStream_t stream) {
    const float* logits_s = (const float*)d_in[0];
    const float* logits_o = (const float*)d_in[1];
    const float* boxes_s  = (const float*)d_in[2];
    const float* boxes_o  = (const float*)d_in[3];
    const float* tbb_s    = (const float*)d_in[4];
    const float* tbb_o    = (const float*)d_in[5];
    const int*   tids_s   = (const int*)d_in[6];
    const int*   tids_o   = (const int*)d_in[7];

    float* out = (float*)d_out;
    float* C_s = out;
    float* C_o = out + CM_SIZE;
    float* idx_out = out + 2*CM_SIZE;

    const size_t staged_bytes = (size_t)2*BS*T*Q*sizeof(float);  // ~9.8 MB
    const int use_staged = (ws_size >= staged_bytes) ? 1 : 0;
    float* blockT = (float*)d_ws;

    dim3 gridA(Q, BS, 2);
    cost_kernel<<<gridA, 256, 0, stream>>>(logits_s, logits_o, boxes_s, boxes_o,
                                           tbb_s, tbb_o, tids_s, tids_o,
                                           C_s, C_o, blockT, use_staged);

    lsa_kernel<<<64, 64, 0, stream>>>(blockT, C_s, idx_out, use_staged);
}

// Round 2
// 366.531 us; speedup vs baseline: 1.3214x; 1.3214x over previous
//
#include <hip/hip_runtime.h>
#include <math.h>

#define BS 32
#define Q  600
#define NC 152
#define T  32
#define MT (BS*T)                   // 1024 targets total
#define CM_SIZE ((size_t)BS*Q*MT)   // 19660800 elements per cost matrix
#define NSLOT 10                    // ceil(600/64)
#define DINF 1e18

// ---------------------------------------------------------------------------
// Kernel A: build cost matrices. One WAVE per (mat,b,q) row, 4 waves/block.
// Shuffle-based softmax (no block barriers), float4 stores.
// Also stages transposed diagonal blocks [mat][b][t][q] into ws for the LSA.
// ---------------------------------------------------------------------------
__global__ __launch_bounds__(256) void cost_kernel(
    const float* __restrict__ logits_s, const float* __restrict__ logits_o,
    const float* __restrict__ boxes_s,  const float* __restrict__ boxes_o,
    const float* __restrict__ tbb_s,    const float* __restrict__ tbb_o,
    const int*   __restrict__ tids_s,   const int*   __restrict__ tids_o,
    float* __restrict__ C_s, float* __restrict__ C_o,
    float* __restrict__ blockT, int use_staged)
{
    const int w = threadIdx.x >> 6, lane = threadIdx.x & 63;
    const int rowg = blockIdx.x * 4 + w;        // 0..38399
    const int mat = rowg / (BS * Q);
    const int r   = rowg % (BS * Q);
    const int b = r / Q, q = r % Q;

    const float* logits = mat ? logits_o : logits_s;
    const float* boxes  = mat ? boxes_o  : boxes_s;
    const float* tbb    = mat ? tbb_o    : tbb_s;
    const int*   tids   = mat ? tids_o   : tids_s;
    float* C = mat ? C_o : C_s;

    // --- softmax over NC=152 classes, wave-local (3 values per lane) ---
    const float* lrow = logits + (size_t)r * NC;
    const float l0 = (lane       < NC) ? lrow[lane]       : -INFINITY;
    const float l1 = (lane + 64  < NC) ? lrow[lane + 64]  : -INFINITY;
    const float l2 = (lane + 128 < NC) ? lrow[lane + 128] : -INFINITY;
    float m = fmaxf(l0, fmaxf(l1, l2));
    #pragma unroll
    for (int off = 32; off > 0; off >>= 1) m = fmaxf(m, __shfl_xor(m, off));
    const float e0 = expf(l0 - m), e1 = expf(l1 - m), e2 = expf(l2 - m);
    float s = e0 + e1 + e2;
    #pragma unroll
    for (int off = 32; off > 0; off >>= 1) s += __shfl_xor(s, off);
    const float inv = 1.0f / s;

    __shared__ float sprob[4][NC];
    if (lane       < NC) sprob[w][lane]       = e0 * inv;
    if (lane + 64  < NC) sprob[w][lane + 64]  = e1 * inv;
    if (lane + 128 < NC) sprob[w][lane + 128] = e2 * inv;
    __syncthreads();

    const float4 ob = ((const float4*)boxes)[r];
    const float ocx = ob.x, ocy = ob.y, ow = ob.z, oh = ob.w;
    const float ox1 = ocx - 0.5f*ow, oy1 = ocy - 0.5f*oh;
    const float ox2 = ocx + 0.5f*ow, oy2 = ocy + 0.5f*oh;
    const float area1 = (ox2-ox1)*(oy2-oy1);

    float* Crow = C + (size_t)r * MT;
    float* bT   = blockT + ((size_t)mat*BS + b) * T * Q;

    #pragma unroll
    for (int it = 0; it < 4; ++it) {
        const int t0 = it*256 + lane*4;
        const int4 cls4 = ((const int4*)tids)[t0 >> 2];
        float4 res;
        #pragma unroll
        for (int k = 0; k < 4; ++k) {
            const int t = t0 + k;
            const int cls = (&cls4.x)[k];
            const float cc = -sprob[w][cls];

            const float4 tb = ((const float4*)tbb)[t];
            const float cb = fabsf(ocx-tb.x) + fabsf(ocy-tb.y)
                           + fabsf(ow -tb.z) + fabsf(oh -tb.w);

            const float tx1 = tb.x - 0.5f*tb.z, ty1 = tb.y - 0.5f*tb.w;
            const float tx2 = tb.x + 0.5f*tb.z, ty2 = tb.y + 0.5f*tb.w;
            const float area2 = (tx2-tx1)*(ty2-ty1);

            const float ltx = fmaxf(ox1,tx1), lty = fmaxf(oy1,ty1);
            const float rbx = fminf(ox2,tx2), rby = fminf(oy2,ty2);
            const float iw = fmaxf(rbx-ltx, 0.0f), ih = fmaxf(rby-lty, 0.0f);
            const float inter = iw*ih;
            const float uni = area1 + area2 - inter;
            const float iou = inter/uni;

            const float cx1 = fminf(ox1,tx1), cy1 = fminf(oy1,ty1);
            const float cx2 = fmaxf(ox2,tx2), cy2 = fmaxf(oy2,ty2);
            const float cw = fmaxf(cx2-cx1, 0.0f), ch = fmaxf(cy2-cy1, 0.0f);
            const float areac = cw*ch;
            const float giou = iou - (areac - uni)/areac;

            const float cost = cb + cc - giou;
            (&res.x)[k] = cost;
            if (use_staged && (t >> 5) == b) bT[(size_t)(t & 31)*Q + q] = cost;
        }
        ((float4*)Crow)[t0 >> 2] = res;
    }
}

// ---------------------------------------------------------------------------
// Kernel B: Jonker-Volgenant LSA, one wave per problem, register-resident
// per-lane column state (v, minv, way, used, phase-start p mirror).
// Deferred-potential formulation: minv stored as cur + sum(deltas so far);
// u/v updates applied once per phase (exact, every row scanned once per
// phase with phase-start u; free-column v constant within a phase).
// ---------------------------------------------------------------------------
__global__ __launch_bounds__(64) void lsa_kernel(
    const float* __restrict__ blockT, const float* __restrict__ Cbase,
    float* __restrict__ idx_out, int use_staged)
{
    const int prob = blockIdx.x;        // 0..63
    const int mat = prob >> 5, b = prob & 31;
    const int lane = threadIdx.x;

    const float* cbase;
    size_t rowStr, colStr;
    if (use_staged) {
        cbase = blockT + (size_t)prob * T * Q;
        rowStr = Q; colStr = 1;
    } else {
        // block[t][q] = C[b, q, b*T + t]
        cbase = Cbase + (size_t)mat*CM_SIZE + (size_t)b*Q*MT + (size_t)b*T;
        rowStr = 1; colStr = MT;
    }

    __shared__ double u[T + 1];
    __shared__ int p[Q + 1];

    for (int j = lane; j <= Q; j += 64) p[j] = 0;
    if (lane <= T) u[lane] = 0.0;
    __syncthreads();

    double vreg[NSLOT], minv[NSLOT], Dins[NSLOT];
    int wayreg[NSLOT], preg[NSLOT];
    #pragma unroll
    for (int c = 0; c < NSLOT; ++c) { vreg[c] = 0.0; Dins[c] = 0.0; wayreg[c] = 0; }

    for (int i = 1; i <= T; ++i) {
        #pragma unroll
        for (int c = 0; c < NSLOT; ++c) {
            minv[c] = DINF;
            const int q0 = c*64 + lane;
            preg[c] = (q0 < Q) ? p[q0 + 1] : 0;
        }
        unsigned usedmask = 0;
        double Dcum = 0.0;
        int j0 = 0, i0 = i, jfin;

        while (true) {
            if (j0) {  // mark previous argmin column used (owner lane only)
                const int owner = (j0 - 1) & 63, slot = (j0 - 1) >> 6;
                if (lane == owner) { usedmask |= 1u << slot; Dins[slot] = Dcum; }
            }
            const float* crow = cbase + (size_t)(i0 - 1) * rowStr;
            const double u0 = u[i0];   // phase-start value; stable within phase

            double best = DINF; int bestj = Q + 1;
            #pragma unroll
            for (int c = 0; c < NSLOT; ++c) {
                const int q0 = c*64 + lane;
                if (q0 < Q && !(usedmask & (1u << c))) {
                    const double cur = (double)crow[(size_t)q0 * colStr]
                                       + (Dcum - u0 - vreg[c]);
                    if (cur < minv[c]) { minv[c] = cur; wayreg[c] = j0; }
                    if (minv[c] < best) { best = minv[c]; bestj = q0 + 1; }
                }
            }
            // butterfly argmin, lowest-index tie-break (np.argmin semantics)
            #pragma unroll
            for (int off = 32; off > 0; off >>= 1) {
                const double ov = __shfl_xor(best, off);
                const int    oj = __shfl_xor(bestj, off);
                if (ov < best || (ov == best && oj < bestj)) { best = ov; bestj = oj; }
            }
            const int j1 = bestj;      // wave-uniform
            Dcum = best;               // Dcum += delta  (delta = best - oldDcum)

            // p[j1] from register mirror (p constant within phase)
            const int owner1 = (j1 - 1) & 63, slot1 = (j1 - 1) >> 6;
            int pv = 0;
            #pragma unroll
            for (int c = 0; c < NSLOT; ++c) if (slot1 == c) pv = preg[c];
            const int pj1 = __shfl(pv, owner1);
            if (pj1 == 0) { jfin = j1; break; }   // final column never marked used
            j0 = j1; i0 = pj1;
        }

        // ---- phase end: apply deferred u/v updates (pre-augmentation p) ----
        const double Dfin = Dcum;
        #pragma unroll
        for (int c = 0; c < NSLOT; ++c) {
            if (usedmask & (1u << c)) {
                const double dec = Dfin - Dins[c];
                vreg[c] -= dec;
                u[preg[c]] += dec;      // distinct rows across used cols: no race
            }
        }
        if (lane == 0) u[i] += Dfin;    // virtual column 0 carries row i
        __syncthreads();

        // ---- augment: walk way[] back, updating p (reads see phase-start p) --
        int jj = jfin;
        while (jj) {
            const int owner = (jj - 1) & 63, slot = (jj - 1) >> 6;
            int wv = 0;
            #pragma unroll
            for (int c = 0; c < NSLOT; ++c) if (slot == c) wv = wayreg[c];
            const int jw = __shfl(wv, owner);
            int newp;
            if (jw == 0) newp = i;
            else {
                const int ow2 = (jw - 1) & 63, sl2 = (jw - 1) >> 6;
                int pv2 = 0;
                #pragma unroll
                for (int c = 0; c < NSLOT; ++c) if (sl2 == c) pv2 = preg[c];
                newp = __shfl(pv2, ow2);
            }
            if (lane == 0) p[jj] = newp;
            jj = jw;
        }
        __syncthreads();
    }

    // ---- output: compact matched columns in ascending j, ballot prefix ----
    float* pred = idx_out + (size_t)mat * 2 * BS * T;   // ps (mat0) / po (mat1)
    float* tgt  = pred + BS * T;                        // ts / to
    int base = 0;
    #pragma unroll
    for (int c = 0; c < NSLOT; ++c) {
        const int q0 = c*64 + lane;
        const int pj = (q0 < Q) ? p[q0 + 1] : 0;
        const bool mtch = (q0 < Q) && (pj != 0);
        const unsigned long long mask = __ballot(mtch);
        if (mtch) {
            const int pos = base + __popcll(mask & ((1ull << lane) - 1ull));
            pred[b*T + pos] = (float)q0;
            tgt [b*T + pos] = (float)(pj - 1);
        }
        base += __popcll(mask);
    }
}

extern "C" void kernel_launch(void* const* d_in, const int* in_sizes, int n_in,
                              void* d_out, int out_size, void* d_ws, size_t ws_size,
                              hipStream_t stream) {
    const float* logits_s = (const float*)d_in[0];
    const float* logits_o = (const float*)d_in[1];
    const float* boxes_s  = (const float*)d_in[2];
    const float* boxes_o  = (const float*)d_in[3];
    const float* tbb_s    = (const float*)d_in[4];
    const float* tbb_o    = (const float*)d_in[5];
    const int*   tids_s   = (const int*)d_in[6];
    const int*   tids_o   = (const int*)d_in[7];

    float* out = (float*)d_out;
    float* C_s = out;
    float* C_o = out + CM_SIZE;
    float* idx_out = out + 2*CM_SIZE;

    const size_t staged_bytes = (size_t)2*BS*T*Q*sizeof(float);  // ~9.8 MB
    const int use_staged = (ws_size >= staged_bytes) ? 1 : 0;
    float* blockT = (float*)d_ws;

    cost_kernel<<<(2*BS*Q)/4, 256, 0, stream>>>(logits_s, logits_o, boxes_s, boxes_o,
                                                tbb_s, tbb_o, tids_s, tids_o,
                                                C_s, C_o, blockT, use_staged);

    lsa_kernel<<<64, 64, 0, stream>>>(blockT, C_s, idx_out, use_staged);
}

// Round 4
// 295.194 us; speedup vs baseline: 1.6408x; 1.2417x over previous
//
#include <hip/hip_runtime.h>
#include <math.h>

#define BS 32
#define Q  600
#define NC 152
#define T  32
#define MT (BS*T)                   // 1024 targets total
#define CM_SIZE ((size_t)BS*Q*MT)   // 19660800 elements per cost matrix
#define NSLOT 10                    // ceil(600/64)
#define FBIG 1e30f

// ---------------------------------------------------------------------------
// Kernel A: build cost matrices. One WAVE per (mat,b,q) row, 4 waves/block.
// ---------------------------------------------------------------------------
__global__ __launch_bounds__(256) void cost_kernel(
    const float* __restrict__ logits_s, const float* __restrict__ logits_o,
    const float* __restrict__ boxes_s,  const float* __restrict__ boxes_o,
    const float* __restrict__ tbb_s,    const float* __restrict__ tbb_o,
    const int*   __restrict__ tids_s,   const int*   __restrict__ tids_o,
    float* __restrict__ C_s, float* __restrict__ C_o,
    float* __restrict__ blockT, int use_staged)
{
    const int w = threadIdx.x >> 6, lane = threadIdx.x & 63;
    const int rowg = blockIdx.x * 4 + w;        // 0..38399
    const int mat = rowg / (BS * Q);
    const int r   = rowg % (BS * Q);
    const int b = r / Q, q = r % Q;

    const float* logits = mat ? logits_o : logits_s;
    const float* boxes  = mat ? boxes_o  : boxes_s;
    const float* tbb    = mat ? tbb_o    : tbb_s;
    const int*   tids   = mat ? tids_o   : tids_s;
    float* C = mat ? C_o : C_s;

    // --- softmax over NC=152 classes, wave-local ---
    const float* lrow = logits + (size_t)r * NC;
    const float l0 = (lane       < NC) ? lrow[lane]       : -INFINITY;
    const float l1 = (lane + 64  < NC) ? lrow[lane + 64]  : -INFINITY;
    const float l2 = (lane + 128 < NC) ? lrow[lane + 128] : -INFINITY;
    float m = fmaxf(l0, fmaxf(l1, l2));
    #pragma unroll
    for (int off = 32; off > 0; off >>= 1) m = fmaxf(m, __shfl_xor(m, off));
    const float e0 = expf(l0 - m), e1 = expf(l1 - m), e2 = expf(l2 - m);
    float s = e0 + e1 + e2;
    #pragma unroll
    for (int off = 32; off > 0; off >>= 1) s += __shfl_xor(s, off);
    const float inv = 1.0f / s;

    __shared__ float sprob[4][NC];
    if (lane       < NC) sprob[w][lane]       = e0 * inv;
    if (lane + 64  < NC) sprob[w][lane + 64]  = e1 * inv;
    if (lane + 128 < NC) sprob[w][lane + 128] = e2 * inv;
    __syncthreads();

    const float4 ob = ((const float4*)boxes)[r];
    const float ocx = ob.x, ocy = ob.y, ow = ob.z, oh = ob.w;
    const float ox1 = ocx - 0.5f*ow, oy1 = ocy - 0.5f*oh;
    const float ox2 = ocx + 0.5f*ow, oy2 = ocy + 0.5f*oh;
    const float area1 = (ox2-ox1)*(oy2-oy1);

    float* Crow = C + (size_t)r * MT;
    float* bT   = blockT + ((size_t)mat*BS + b) * T * Q;

    #pragma unroll
    for (int it = 0; it < 4; ++it) {
        const int t0 = it*256 + lane*4;
        const int4 cls4 = ((const int4*)tids)[t0 >> 2];
        float4 res;
        #pragma unroll
        for (int k = 0; k < 4; ++k) {
            const int t = t0 + k;
            const int cls = (&cls4.x)[k];
            const float cc = -sprob[w][cls];

            const float4 tb = ((const float4*)tbb)[t];
            const float cb = fabsf(ocx-tb.x) + fabsf(ocy-tb.y)
                           + fabsf(ow -tb.z) + fabsf(oh -tb.w);

            const float tx1 = tb.x - 0.5f*tb.z, ty1 = tb.y - 0.5f*tb.w;
            const float tx2 = tb.x + 0.5f*tb.z, ty2 = tb.y + 0.5f*tb.w;
            const float area2 = (tx2-tx1)*(ty2-ty1);

            const float ltx = fmaxf(ox1,tx1), lty = fmaxf(oy1,ty1);
            const float rbx = fminf(ox2,tx2), rby = fminf(oy2,ty2);
            const float iw = fmaxf(rbx-ltx, 0.0f), ih = fmaxf(rby-lty, 0.0f);
            const float inter = iw*ih;
            const float uni = area1 + area2 - inter;
            const float iou = inter/uni;

            const float cx1 = fminf(ox1,tx1), cy1 = fminf(oy1,ty1);
            const float cx2 = fmaxf(ox2,tx2), cy2 = fmaxf(oy2,ty2);
            const float cw = fmaxf(cx2-cx1, 0.0f), ch = fmaxf(cy2-cy1, 0.0f);
            const float areac = cw*ch;
            const float giou = iou - (areac - uni)/areac;

            const float cost = cb + cc - giou;
            (&res.x)[k] = cost;
            if (use_staged && (t >> 5) == b) bT[(size_t)(t & 31)*Q + q] = cost;
        }
        ((float4*)Crow)[t0 >> 2] = res;
    }
}

// ---------------------------------------------------------------------------
// DPP wave-min over u64 keys (VALU pipe only; result broadcast via readlane 63)
// ---------------------------------------------------------------------------
__device__ __forceinline__ unsigned long long wave_min_u64(unsigned long long k) {
  #define STAGE(CTRL, RMASK) { \
    int lo = (int)(unsigned)(k & 0xffffffffull); \
    int hi = (int)(unsigned)(k >> 32); \
    int plo = __builtin_amdgcn_update_dpp(lo, lo, CTRL, RMASK, 0xF, false); \
    int phi = __builtin_amdgcn_update_dpp(hi, hi, CTRL, RMASK, 0xF, false); \
    unsigned long long p = ((unsigned long long)(unsigned)phi << 32) | (unsigned)plo; \
    k = (p < k) ? p : k; }
  STAGE(0xB1, 0xF)   // quad_perm [1,0,3,2]  : xor 1
  STAGE(0x4E, 0xF)   // quad_perm [2,3,0,1]  : xor 2
  STAGE(0x141, 0xF)  // row_half_mirror      : xor 4
  STAGE(0x140, 0xF)  // row_mirror           : xor 8
  STAGE(0x142, 0xA)  // row_bcast15 -> rows 1,3
  STAGE(0x143, 0xC)  // row_bcast31 -> rows 2,3
  #undef STAGE
  unsigned lo63 = (unsigned)__builtin_amdgcn_readlane((int)(unsigned)(k & 0xffffffffull), 63);
  unsigned hi63 = (unsigned)__builtin_amdgcn_readlane((int)(unsigned)(k >> 32), 63);
  return ((unsigned long long)hi63 << 32) | lo63;
}

__device__ __forceinline__ unsigned f32_sortable(float f) {
  unsigned u = __float_as_uint(f);
  return u ^ ((unsigned)((int)u >> 31) | 0x80000000u);
}
__device__ __forceinline__ float f32_unsortable(unsigned s) {
  unsigned m = (unsigned)((int)(~s) >> 31) | 0x80000000u;
  return __uint_as_float(s ^ m);
}

// ---------------------------------------------------------------------------
// Kernel B: Jonker-Volgenant LSA, one wave per problem. f32, register state,
// DPP argmin with packed (dist, j, p[j]) key, EXPLICIT per-lane used mask.
// (Round-3 post-mortem: the implicit "minv > Dsel" used-test is unsound in
// f32 — the scanned row's own matched column has reduced cost exactly 0 and
// a 1-ulp-low rounding writes way[j]=j, a self-loop that hangs the augment
// walk. The explicit mask below gates both the minv/way update and argmin.)
// ---------------------------------------------------------------------------
__global__ __launch_bounds__(64) void lsa_kernel(
    const float* __restrict__ blockT, const float* __restrict__ Cbase,
    float* __restrict__ idx_out, int use_staged)
{
    const int prob = blockIdx.x;        // 0..63
    const int mat = prob >> 5, b = prob & 31;
    const int lane = threadIdx.x;

    const float* cb;
    size_t rowStr, colStr;
    if (use_staged) {
        cb = blockT + (size_t)prob * T * Q;
        rowStr = Q; colStr = 1;
    } else {
        cb = Cbase + (size_t)mat*CM_SIZE + (size_t)b*Q*MT + (size_t)b*T;
        rowStr = 1; colStr = MT;
    }

    __shared__ float u_s[T + 1];
    __shared__ int   p_s[Q + 1];

    for (int j = lane; j <= Q; j += 64) p_s[j] = 0;
    if (lane <= T) u_s[lane] = 0.0f;
    __syncthreads();

    float vreg[NSLOT], minv[NSLOT];
    int   wayreg[NSLOT], low[NSLOT];
    #pragma unroll
    for (int c = 0; c < NSLOT; ++c) vreg[c] = 0.0f;

    for (int i = 1; i <= T; ++i) {
        // ---- phase init: snapshot p into packed low bits, reset minv/way ----
        #pragma unroll
        for (int c = 0; c < NSLOT; ++c) {
            const int q0 = c*64 + lane;
            minv[c] = FBIG;
            wayreg[c] = 0;
            low[c] = (q0 < Q) ? (((q0 + 1) << 6) | p_s[q0 + 1]) : 0x3FFFFF;
        }
        unsigned usedmask = 0;
        float Dcum = 0.0f;        // cumulative-delta shift for the scan
        int j0 = 0, i0 = i, jfin;

        while (true) {
            const float u0 = u_s[i0];
            const float* crow = cb + (size_t)(i0 - 1) * rowStr;

            float cst[NSLOT];
            #pragma unroll
            for (int c = 0; c < NSLOT; ++c) {
                const int q0 = c*64 + lane;
                cst[c] = (q0 < Q) ? crow[(size_t)q0 * colStr] : FBIG;
            }
            const float sh = Dcum - u0;

            float best = FBIG; int blow = 0x3FFFFF;
            #pragma unroll
            for (int c = 0; c < NSLOT; ++c) {
                const bool fre = !((usedmask >> c) & 1u);
                const float cur = (cst[c] - vreg[c]) + sh;
                const bool upd = fre && (cur < minv[c]);
                wayreg[c] = upd ? j0 : wayreg[c];
                minv[c]   = upd ? cur : minv[c];
                const bool inc = fre && (minv[c] < best);
                best = inc ? minv[c] : best;
                blow = inc ? low[c] : blow;
            }

            unsigned long long key =
                ((unsigned long long)f32_sortable(best) << 22) | (unsigned)blow;
            key = wave_min_u64(key);

            Dcum = f32_unsortable((unsigned)(key >> 22));
            const int j1  = (int)((key >> 6) & 0x3FF);
            const int pj1 = (int)(key & 0x3F);

            if (pj1 == 0) { jfin = j1; break; }
            // mark j1 used (owner lane's bit); its frozen minv == Dins
            const int owner1 = (j1 - 1) & 63, slot1 = (j1 - 1) >> 6;
            if (lane == owner1) usedmask |= 1u << slot1;
            j0 = j1; i0 = pj1;
        }

        // ---- phase end: deferred u/v updates (frozen minv[c] == Dins[c]) ----
        const float Dfin = Dcum;
        #pragma unroll
        for (int c = 0; c < NSLOT; ++c) {
            if ((usedmask >> c) & 1u) {
                const float dec = Dfin - minv[c];
                vreg[c] -= dec;
                u_s[low[c] & 63] += dec;     // distinct rows -> no collision
            }
        }
        if (lane == 0) u_s[i] += Dfin;
        __syncthreads();

        // ---- augment: walk way[] back, updating p (reads = phase-start snap) --
        int jj = jfin;
        while (jj) {
            const int owner = (jj - 1) & 63, slot = (jj - 1) >> 6;
            int wv = 0;
            #pragma unroll
            for (int c = 0; c < NSLOT; ++c) if (slot == c) wv = wayreg[c];
            const int jw = __shfl(wv, owner);
            int newp;
            if (jw == 0) newp = i;
            else {
                const int ow2 = (jw - 1) & 63, sl2 = (jw - 1) >> 6;
                int pv2 = 0;
                #pragma unroll
                for (int c = 0; c < NSLOT; ++c) if (sl2 == c) pv2 = low[c] & 63;
                newp = __shfl(pv2, ow2);
            }
            if (lane == 0) p_s[jj] = newp;
            jj = jw;
        }
        __syncthreads();
    }

    // ---- output: compact matched columns in ascending j, ballot prefix ----
    float* pred = idx_out + (size_t)mat * 2 * BS * T;   // ps (mat0) / po (mat1)
    float* tgt  = pred + BS * T;                        // ts / to
    int base = 0;
    #pragma unroll
    for (int c = 0; c < NSLOT; ++c) {
        const int q0 = c*64 + lane;
        const int pj = (q0 < Q) ? p_s[q0 + 1] : 0;
        const bool mtch = (q0 < Q) && (pj != 0);
        const unsigned long long mask = __ballot(mtch);
        if (mtch) {
            const int pos = base + __popcll(mask & ((1ull << lane) - 1ull));
            pred[b*T + pos] = (float)q0;
            tgt [b*T + pos] = (float)(pj - 1);
        }
        base += __popcll(mask);
    }
}

extern "C" void kernel_launch(void* const* d_in, const int* in_sizes, int n_in,
                              void* d_out, int out_size, void* d_ws, size_t ws_size,
                              hipStream_t stream) {
    const float* logits_s = (const float*)d_in[0];
    const float* logits_o = (const float*)d_in[1];
    const float* boxes_s  = (const float*)d_in[2];
    const float* boxes_o  = (const float*)d_in[3];
    const float* tbb_s    = (const float*)d_in[4];
    const float* tbb_o    = (const float*)d_in[5];
    const int*   tids_s   = (const int*)d_in[6];
    const int*   tids_o   = (const int*)d_in[7];

    float* out = (float*)d_out;
    float* C_s = out;
    float* C_o = out + CM_SIZE;
    float* idx_out = out + 2*CM_SIZE;

    const size_t staged_bytes = (size_t)2*BS*T*Q*sizeof(float);  // ~9.8 MB
    const int use_staged = (ws_size >= staged_bytes) ? 1 : 0;
    float* blockT = (float*)d_ws;

    cost_kernel<<<(2*BS*Q)/4, 256, 0, stream>>>(logits_s, logits_o, boxes_s, boxes_o,
                                                tbb_s, tbb_o, tids_s, tids_o,
                                                C_s, C_o, blockT, use_staged);

    lsa_kernel<<<64, 64, 0, stream>>>(blockT, C_s, idx_out, use_staged);
}

// Round 6
// 294.182 us; speedup vs baseline: 1.6464x; 1.0034x over previous
//
#include <hip/hip_runtime.h>
#include <math.h>

#define BS 32
#define Q  600
#define NC 152
#define T  32
#define MT (BS*T)                   // 1024 targets total
#define CM_SIZE ((size_t)BS*Q*MT)   // 19660800 elements per cost matrix
#define NSLOT 10                    // ceil(600/64)
#define FBIG 1e30f

typedef float vfloat4 __attribute__((ext_vector_type(4)));  // clang-native for nt-store

// ---------------------------------------------------------------------------
// Kernel A: build cost matrices. One WAVE per (mat,b,q) row, 4 waves/block.
// VALU-lean: fast rcp instead of IEEE divide, area = w*h, no dead clamps,
// staging predicate hoisted, nontemporal C stores.
// ---------------------------------------------------------------------------
__global__ __launch_bounds__(256) void cost_kernel(
    const float* __restrict__ logits_s, const float* __restrict__ logits_o,
    const float* __restrict__ boxes_s,  const float* __restrict__ boxes_o,
    const float* __restrict__ tbb_s,    const float* __restrict__ tbb_o,
    const int*   __restrict__ tids_s,   const int*   __restrict__ tids_o,
    float* __restrict__ C_s, float* __restrict__ C_o,
    float* __restrict__ blockT, int use_staged)
{
    const int w = threadIdx.x >> 6, lane = threadIdx.x & 63;
    const int rowg = blockIdx.x * 4 + w;        // 0..38399
    const int mat = rowg / (BS * Q);
    const int r   = rowg % (BS * Q);
    const int b = r / Q, q = r % Q;

    const float* logits = mat ? logits_o : logits_s;
    const float* boxes  = mat ? boxes_o  : boxes_s;
    const float* tbb    = mat ? tbb_o    : tbb_s;
    const int*   tids   = mat ? tids_o   : tids_s;
    float* C = mat ? C_o : C_s;

    // --- softmax over NC=152 classes, wave-local ---
    const float* lrow = logits + (size_t)r * NC;
    const float l0 = (lane       < NC) ? lrow[lane]       : -INFINITY;
    const float l1 = (lane + 64  < NC) ? lrow[lane + 64]  : -INFINITY;
    const float l2 = (lane + 128 < NC) ? lrow[lane + 128] : -INFINITY;
    float m = fmaxf(l0, fmaxf(l1, l2));
    #pragma unroll
    for (int off = 32; off > 0; off >>= 1) m = fmaxf(m, __shfl_xor(m, off));
    const float e0 = expf(l0 - m), e1 = expf(l1 - m), e2 = expf(l2 - m);
    float s = e0 + e1 + e2;
    #pragma unroll
    for (int off = 32; off > 0; off >>= 1) s += __shfl_xor(s, off);
    const float inv = 1.0f / s;

    __shared__ float sprob[4][NC];
    if (lane       < NC) sprob[w][lane]       = e0 * inv;
    if (lane + 64  < NC) sprob[w][lane + 64]  = e1 * inv;
    if (lane + 128 < NC) sprob[w][lane + 128] = e2 * inv;
    __syncthreads();

    const float4 ob = ((const float4*)boxes)[r];
    const float ocx = ob.x, ocy = ob.y, ow = ob.z, oh = ob.w;
    const float ox1 = ocx - 0.5f*ow, oy1 = ocy - 0.5f*oh;
    const float ox2 = ocx + 0.5f*ow, oy2 = ocy + 0.5f*oh;
    const float area1 = ow * oh;

    float* Crow = C + (size_t)r * MT;
    float* bT   = blockT + ((size_t)mat*BS + b) * T * Q;

    #pragma unroll
    for (int it = 0; it < 4; ++it) {
        const int t0 = it*256 + lane*4;
        const int4 cls4 = ((const int4*)tids)[t0 >> 2];
        // 4-aligned chunk never crosses a 32-boundary -> (t>>5) uniform over k
        const bool stg = use_staged && ((t0 >> 5) == b);
        vfloat4 res;
        #pragma unroll
        for (int k = 0; k < 4; ++k) {
            const int t = t0 + k;
            const int cls = (&cls4.x)[k];
            const float cc = -sprob[w][cls];

            const float4 tb = ((const float4*)tbb)[t];
            const float cb = fabsf(ocx-tb.x) + fabsf(ocy-tb.y)
                           + fabsf(ow -tb.z) + fabsf(oh -tb.w);

            const float tx1 = fmaf(-0.5f, tb.z, tb.x), ty1 = fmaf(-0.5f, tb.w, tb.y);
            const float tx2 = fmaf( 0.5f, tb.z, tb.x), ty2 = fmaf( 0.5f, tb.w, tb.y);
            const float area2 = tb.z * tb.w;

            const float ltx = fmaxf(ox1,tx1), lty = fmaxf(oy1,ty1);
            const float rbx = fminf(ox2,tx2), rby = fminf(oy2,ty2);
            const float iw = fmaxf(rbx-ltx, 0.0f), ih = fmaxf(rby-lty, 0.0f);
            const float inter = iw*ih;
            const float uni = area1 + area2 - inter;

            const float cx1 = fminf(ox1,tx1), cy1 = fminf(oy1,ty1);
            const float cx2 = fmaxf(ox2,tx2), cy2 = fmaxf(oy2,ty2);
            const float areac = (cx2-cx1)*(cy2-cy1);   // >= 0 by construction

            // giou = inter/uni - (areac-uni)/areac, via fast rcp (+-1 ulp)
            const float giou = inter * __builtin_amdgcn_rcpf(uni)
                             - (areac - uni) * __builtin_amdgcn_rcpf(areac);

            const float cost = cb + cc - giou;
            res[k] = cost;
            if (stg) bT[(size_t)(t & 31)*Q + q] = cost;
        }
        __builtin_nontemporal_store(res, (vfloat4*)(Crow + t0));
    }
}

// ---------------------------------------------------------------------------
// DPP wave-min over u64 keys (VALU pipe only; result broadcast via readlane 63)
// ---------------------------------------------------------------------------
__device__ __forceinline__ unsigned long long wave_min_u64(unsigned long long k) {
  #define STAGE(CTRL, RMASK) { \
    int lo = (int)(unsigned)(k & 0xffffffffull); \
    int hi = (int)(unsigned)(k >> 32); \
    int plo = __builtin_amdgcn_update_dpp(lo, lo, CTRL, RMASK, 0xF, false); \
    int phi = __builtin_amdgcn_update_dpp(hi, hi, CTRL, RMASK, 0xF, false); \
    unsigned long long p = ((unsigned long long)(unsigned)phi << 32) | (unsigned)plo; \
    k = (p < k) ? p : k; }
  STAGE(0xB1, 0xF)   // quad_perm [1,0,3,2]  : xor 1
  STAGE(0x4E, 0xF)   // quad_perm [2,3,0,1]  : xor 2
  STAGE(0x141, 0xF)  // row_half_mirror      : xor 4
  STAGE(0x140, 0xF)  // row_mirror           : xor 8
  STAGE(0x142, 0xA)  // row_bcast15 -> rows 1,3
  STAGE(0x143, 0xC)  // row_bcast31 -> rows 2,3
  #undef STAGE
  unsigned lo63 = (unsigned)__builtin_amdgcn_readlane((int)(unsigned)(k & 0xffffffffull), 63);
  unsigned hi63 = (unsigned)__builtin_amdgcn_readlane((int)(unsigned)(k >> 32), 63);
  return ((unsigned long long)hi63 << 32) | lo63;
}

__device__ __forceinline__ unsigned f32_sortable(float f) {
  unsigned u = __float_as_uint(f);
  return u ^ ((unsigned)((int)u >> 31) | 0x80000000u);
}
__device__ __forceinline__ float f32_unsortable(unsigned s) {
  unsigned m = (unsigned)((int)(~s) >> 31) | 0x80000000u;
  return __uint_as_float(s ^ m);
}

// ---------------------------------------------------------------------------
// Kernel B: Jonker-Volgenant LSA, one wave per problem. f32, register state,
// DPP argmin with packed (dist, j, p[j]) key, EXPLICIT per-lane used mask.
// ---------------------------------------------------------------------------
__global__ __launch_bounds__(64) void lsa_kernel(
    const float* __restrict__ blockT, const float* __restrict__ Cbase,
    float* __restrict__ idx_out, int use_staged)
{
    const int prob = blockIdx.x;        // 0..63
    const int mat = prob >> 5, b = prob & 31;
    const int lane = threadIdx.x;

    const float* cb;
    size_t rowStr, colStr;
    if (use_staged) {
        cb = blockT + (size_t)prob * T * Q;
        rowStr = Q; colStr = 1;
    } else {
        cb = Cbase + (size_t)mat*CM_SIZE + (size_t)b*Q*MT + (size_t)b*T;
        rowStr = 1; colStr = MT;
    }

    __shared__ float u_s[T + 1];
    __shared__ int   p_s[Q + 1];

    for (int j = lane; j <= Q; j += 64) p_s[j] = 0;
    if (lane <= T) u_s[lane] = 0.0f;
    __syncthreads();

    float vreg[NSLOT], minv[NSLOT];
    int   wayreg[NSLOT], low[NSLOT];
    #pragma unroll
    for (int c = 0; c < NSLOT; ++c) vreg[c] = 0.0f;

    for (int i = 1; i <= T; ++i) {
        #pragma unroll
        for (int c = 0; c < NSLOT; ++c) {
            const int q0 = c*64 + lane;
            minv[c] = FBIG;
            wayreg[c] = 0;
            low[c] = (q0 < Q) ? (((q0 + 1) << 6) | p_s[q0 + 1]) : 0x3FFFFF;
        }
        unsigned usedmask = 0;
        float Dcum = 0.0f;
        int j0 = 0, i0 = i, jfin;

        while (true) {
            const float u0 = u_s[i0];
            const float* crow = cb + (size_t)(i0 - 1) * rowStr;

            float cst[NSLOT];
            #pragma unroll
            for (int c = 0; c < NSLOT; ++c) {
                const int q0 = c*64 + lane;
                cst[c] = (q0 < Q) ? crow[(size_t)q0 * colStr] : FBIG;
            }
            const float sh = Dcum - u0;

            float best = FBIG; int blow = 0x3FFFFF;
            #pragma unroll
            for (int c = 0; c < NSLOT; ++c) {
                const bool fre = !((usedmask >> c) & 1u);
                const float cur = (cst[c] - vreg[c]) + sh;
                const bool upd = fre && (cur < minv[c]);
                wayreg[c] = upd ? j0 : wayreg[c];
                minv[c]   = upd ? cur : minv[c];
                const bool inc = fre && (minv[c] < best);
                best = inc ? minv[c] : best;
                blow = inc ? low[c] : blow;
            }

            unsigned long long key =
                ((unsigned long long)f32_sortable(best) << 22) | (unsigned)blow;
            key = wave_min_u64(key);

            Dcum = f32_unsortable((unsigned)(key >> 22));
            const int j1  = (int)((key >> 6) & 0x3FF);
            const int pj1 = (int)(key & 0x3F);

            if (pj1 == 0) { jfin = j1; break; }
            const int owner1 = (j1 - 1) & 63, slot1 = (j1 - 1) >> 6;
            if (lane == owner1) usedmask |= 1u << slot1;
            j0 = j1; i0 = pj1;
        }

        const float Dfin = Dcum;
        #pragma unroll
        for (int c = 0; c < NSLOT; ++c) {
            if ((usedmask >> c) & 1u) {
                const float dec = Dfin - minv[c];
                vreg[c] -= dec;
                u_s[low[c] & 63] += dec;     // distinct rows -> no collision
            }
        }
        if (lane == 0) u_s[i] += Dfin;
        __syncthreads();

        int jj = jfin;
        while (jj) {
            const int owner = (jj - 1) & 63, slot = (jj - 1) >> 6;
            int wv = 0;
            #pragma unroll
            for (int c = 0; c < NSLOT; ++c) if (slot == c) wv = wayreg[c];
            const int jw = __shfl(wv, owner);
            int newp;
            if (jw == 0) newp = i;
            else {
                const int ow2 = (jw - 1) & 63, sl2 = (jw - 1) >> 6;
                int pv2 = 0;
                #pragma unroll
                for (int c = 0; c < NSLOT; ++c) if (sl2 == c) pv2 = low[c] & 63;
                newp = __shfl(pv2, ow2);
            }
            if (lane == 0) p_s[jj] = newp;
            jj = jw;
        }
        __syncthreads();
    }

    float* pred = idx_out + (size_t)mat * 2 * BS * T;   // ps (mat0) / po (mat1)
    float* tgt  = pred + BS * T;                        // ts / to
    int base = 0;
    #pragma unroll
    for (int c = 0; c < NSLOT; ++c) {
        const int q0 = c*64 + lane;
        const int pj = (q0 < Q) ? p_s[q0 + 1] : 0;
        const bool mtch = (q0 < Q) && (pj != 0);
        const unsigned long long mask = __ballot(mtch);
        if (mtch) {
            const int pos = base + __popcll(mask & ((1ull << lane) - 1ull));
            pred[b*T + pos] = (float)q0;
            tgt [b*T + pos] = (float)(pj - 1);
        }
        base += __popcll(mask);
    }
}

extern "C" void kernel_launch(void* const* d_in, const int* in_sizes, int n_in,
                              void* d_out, int out_size, void* d_ws, size_t ws_size,
                              hipStream_t stream) {
    const float* logits_s = (const float*)d_in[0];
    const float* logits_o = (const float*)d_in[1];
    const float* boxes_s  = (const float*)d_in[2];
    const float* boxes_o  = (const float*)d_in[3];
    const float* tbb_s    = (const float*)d_in[4];
    const float* tbb_o    = (const float*)d_in[5];
    const int*   tids_s   = (const int*)d_in[6];
    const int*   tids_o   = (const int*)d_in[7];

    float* out = (float*)d_out;
    float* C_s = out;
    float* C_o = out + CM_SIZE;
    float* idx_out = out + 2*CM_SIZE;

    const size_t staged_bytes = (size_t)2*BS*T*Q*sizeof(float);  // ~9.8 MB
    const int use_staged = (ws_size >= staged_bytes) ? 1 : 0;
    float* blockT = (float*)d_ws;

    cost_kernel<<<(2*BS*Q)/4, 256, 0, stream>>>(logits_s, logits_o, boxes_s, boxes_o,
                                                tbb_s, tbb_o, tids_s, tids_o,
                                                C_s, C_o, blockT, use_staged);

    lsa_kernel<<<64, 64, 0, stream>>>(blockT, C_s, idx_out, use_staged);
}